// Round 5
// baseline (82.571 us; speedup 1.0000x reference)
//
#include <hip/hip_runtime.h>

// NEUROPULS unitary mesh, N=256 — R8: split coefficient production into a
// separate kernel; the mesh wave consumes ready-made coefficients.
// R7 post-mortem: per-stage cost stuck at ~750 cy across R4/R6/R7 despite
// removing ~80 VALU ops/stage — the wave's instruction stream is effectively
// fully serialized (VALUBusy 12% = ~49% issue on the single busy SIMD) and
// the theta-load + 8 sincos + coef prep never leave the chain. Also: the
// coefficients depend only on theta, which is SHARED by all 256 columns —
// 256x redundant recomputation.
// Fix: kernel 1 (128 blocks x 64 lanes) computes the collapsed-operator
// coefficients for all stages once -> workspace (384 KB, L2-resident).
// Kernel 2 (mesh) per stage: 3 coalesced dwordx4 loads (3-stage-deep
// prefetch, state-independent) + 32 FMA mstep + ~20 VALU crossing. No
// transcendentals on the chain.
// Coef layout (float4 units): group g in {A,B,C} at g*8192 + (s-1)*64 + lane.
//   A=(Er0,Ei0,Fr0,Fi0)  B=(Gr0,Gi0,Gr1,Gi1)  C=(Er1,Ei1,Fr1,Fi1)
// for pairs (4l,4l+1),(4l+2,4l+3);  E=U*p0-W*p1, F=U*p1-W*p0, G=i*g*(p0+p1),
// U=AT^2, W=AR^2, g=AT*AR  (verified algebra, R6 passed).

__device__ __forceinline__ float dpp_up1(float x) {
    // lane n <- lane n-1 (wave_shr:1); lane 0 keeps old, masked later
    return __int_as_float(__builtin_amdgcn_update_dpp(
        __float_as_int(x), __float_as_int(x), 0x138, 0xf, 0xf, false));
}
__device__ __forceinline__ float dpp_dn1(float x) {
    // lane n <- lane n+1 (wave_shl:1); lane 63 keeps old, masked later
    return __int_as_float(__builtin_amdgcn_update_dpp(
        __float_as_int(x), __float_as_int(x), 0x130, 0xf, 0xf, false));
}

__device__ __forceinline__ void sincos4(float4 th, float sn[4], float cs[4]) {
    __sincosf(th.x, &sn[0], &cs[0]);
    __sincosf(th.y, &sn[1], &cs[1]);
    __sincosf(th.z, &sn[2], &cs[2]);
    __sincosf(th.w, &sn[3], &cs[3]);
}

// ---------- kernel 1: per-stage collapsed coefficients ----------
__global__ __launch_bounds__(64)
void coef_kernel(const float* __restrict__ thetas,  // [130,256]
                 float* __restrict__ coefs)         // ws: 3*128*64 float4
{
    const int s0   = blockIdx.x;    // 0..127 -> stage s = s0+1 (theta row s0+1)
    const int lane = threadIdx.x;   // 0..63

    const float U  = 0.98f * 0.505f;                  // AT^2
    const float W  = 0.98f * 0.495f;                  // AR^2
    const float Gc = 0.98f * sqrtf(0.505f * 0.495f);  // AT*AR

    float4 th = *(const float4*)(thetas + (s0 + 1) * 256 + 4 * lane);
    float s[4], c[4];
    sincos4(th, s, c);

    float4 A, B, C;
    A.x = U * c[0] - W * c[1];   A.y = U * s[0] - W * s[1];   // E0
    A.z = U * c[1] - W * c[0];   A.w = U * s[1] - W * s[0];   // F0
    B.x = -Gc * (s[0] + s[1]);   B.y = Gc * (c[0] + c[1]);    // G0
    B.z = -Gc * (s[2] + s[3]);   B.w = Gc * (c[2] + c[3]);    // G1
    C.x = U * c[2] - W * c[3];   C.y = U * s[2] - W * s[3];   // E1
    C.z = U * c[3] - W * c[2];   C.w = U * s[3] - W * s[2];   // F1

    float4* cp = (float4*)coefs;
    cp[0 * 8192 + s0 * 64 + lane] = A;
    cp[1 * 8192 + s0 * 64 + lane] = B;
    cp[2 * 8192 + s0 * 64 + lane] = C;
}

// ---------- kernel 2: mesh state chain ----------
__global__ __launch_bounds__(64, 1)
void neuropuls_mesh_kernel(const float* __restrict__ thetas,  // [130,256]
                           const float* __restrict__ coefs,   // ws (from k1)
                           float* __restrict__ out)           // re[65536] || im[65536]
{
    constexpr int N = 256;
    const int lane = threadIdx.x;   // 0..63
    const int col  = blockIdx.x;    // 0..255

    const float BT = sqrtf(0.98f * 0.01f);   // CR a*sqrt(CT)
    const float BR = sqrtf(0.98f * 0.99f);   // CR a*sqrt(1-CT) == thru

    float vr[4] = {0.f, 0.f, 0.f, 0.f};
    float vi[4] = {0.f, 0.f, 0.f, 0.f};

    // arch0 = diag(exp(i*theta[0]))
    {
        const float th0 = thetas[col];
        float s0, c0;
        __sincosf(th0, &s0, &c0);
        const int r0 = col - 4 * lane;
        if (0 <= r0 && r0 < 4) { vr[r0] = c0; vi[r0] = s0; }
    }

    // mstep: collapsed MMI*diag*MMI on pairs (0,1),(2,3) from packed coefs
    auto mstep = [&](const float4 A, const float4 B, const float4 C) {
        {   // pair 0: E=A.xy F=A.zw G=B.xy
            const float xr = vr[0], xi = vi[0], yr = vr[1], yi = vi[1];
            vr[0] = A.x * xr - A.y * xi + B.x * yr - B.y * yi;
            vi[0] = A.x * xi + A.y * xr + B.x * yi + B.y * yr;
            vr[1] = B.x * xr - B.y * xi + A.z * yr - A.w * yi;
            vi[1] = B.x * xi + B.y * xr + A.z * yi + A.w * yr;
        }
        {   // pair 1: E=C.xy F=C.zw G=B.zw
            const float xr = vr[2], xi = vi[2], yr = vr[3], yi = vi[3];
            vr[2] = C.x * xr - C.y * xi + B.z * yr - B.w * yi;
            vi[2] = C.x * xi + C.y * xr + B.z * yi + B.w * yr;
            vr[3] = B.z * xr - B.w * xi + C.z * yr - C.w * yi;
            vi[3] = B.z * xi + B.w * xr + C.z * yi + C.w * yr;
        }
    };

    auto crossing = [&]() {
        float pv3r = dpp_up1(vr[3]);
        float pv3i = dpp_up1(vi[3]);
        float nv0r = dpp_dn1(vr[0]);
        float nv0i = dpp_dn1(vi[0]);
        {   // internal odd pair (4t+1, 4t+2)
            float xr = vr[1], xi = vi[1], yr = vr[2], yi = vi[2];
            vr[1] = BT * xr - BR * yi;  vi[1] = BT * xi + BR * yr;
            vr[2] = BT * yr - BR * xi;  vi[2] = BT * yi + BR * xr;
        }
        {   // pair (4t-1, 4t): lane 0 row 0 = thru
            float yr = vr[0], yi = vi[0];
            float nr = BT * yr - BR * pv3i;
            float ni = BT * yi + BR * pv3r;
            vr[0] = (lane == 0) ? BR * yr : nr;
            vi[0] = (lane == 0) ? BR * yi : ni;
        }
        {   // pair (4t+3, 4t+4): lane 63 row 255 = thru
            float xr = vr[3], xi = vi[3];
            float nr = BT * xr - BR * nv0i;
            float ni = BT * xi + BR * nv0r;
            vr[3] = (lane == 63) ? BR * xr : nr;
            vi[3] = (lane == 63) ? BR * xi : ni;
        }
    };

    // Coef pointers (uniform base + lane offset; stage advances by 64 float4)
    const float4* pA = (const float4*)coefs + lane;          // group A
    const float4* pB = (const float4*)coefs + 8192 + lane;   // group B
    const float4* pC = (const float4*)coefs + 16384 + lane;  // group C

    // ---- 3-deep coefficient prefetch pipeline ----
    float4 A0 = pA[0],   B0 = pB[0],   C0 = pC[0];    // stage 1
    float4 A1 = pA[64],  B1 = pB[64],  C1 = pC[64];   // stage 2
    float4 A2 = pA[128], B2 = pB[128], C2 = pC[128];  // stage 3
    pA += 192; pB += 192; pC += 192;

    // crossing stages s = 1..126 (127th after the loop); 126 = 42*3
    #pragma unroll 3
    for (int s = 1; s <= 126; ++s) {
        // stage s+3 coefs in flight (s=126 reads 1 KB past group C — lands
        // inside the 256 MB ws, value never consumed)
        float4 A3 = pA[0], B3 = pB[0], C3 = pC[0];
        pA += 64; pB += 64; pC += 64;
        // serial state chain, coefficients ready
        mstep(A0, B0, C0);
        crossing();
        // rotate (renamed by unroll 3)
        A0 = A1; B0 = B1; C0 = C1;
        A1 = A2; B1 = B2; C1 = C2;
        A2 = A3; B2 = B3; C2 = C3;
    }

    // stage 127 (last crossing stage)
    mstep(A0, B0, C0);
    crossing();

    // stage 128: mstep only
    mstep(A1, B1, C1);

    // final phase layer theta[129]
    {
        float4 thF = *(const float4*)(thetas + 129 * N + 4 * lane);
        float sn[4], cs[4];
        sincos4(thF, sn, cs);
        #pragma unroll
        for (int j = 0; j < 4; ++j) {
            float r = vr[j], i = vi[j];
            vr[j] = cs[j] * r - sn[j] * i;
            vi[j] = cs[j] * i + sn[j] * r;
        }
    }

    // store PLANAR: real block then imag block, each row-major [row][col]
    #pragma unroll
    for (int j = 0; j < 4; ++j) {
        const int idx = (4 * lane + j) * N + col;
        out[idx]         = vr[j];
        out[N * N + idx] = vi[j];
    }
}

extern "C" void kernel_launch(void* const* d_in, const int* in_sizes, int n_in,
                              void* d_out, int out_size, void* d_ws, size_t ws_size,
                              hipStream_t stream)
{
    const float* thetas = (const float*)d_in[0];   // [130,256] fp32
    float* out   = (float*)d_out;                  // planar: re[65536] || im[65536]
    float* coefs = (float*)d_ws;                   // 3*128*64 float4 = 384 KB
    (void)in_sizes; (void)n_in; (void)out_size; (void)ws_size;

    coef_kernel<<<dim3(128), dim3(64), 0, stream>>>(thetas, coefs);
    neuropuls_mesh_kernel<<<dim3(256), dim3(64), 0, stream>>>(thetas, coefs, out);
}